// Round 2
// baseline (9228.811 us; speedup 1.0000x reference)
//
#include <hip/hip_runtime.h>
#include <cmath>

typedef float  f32x4  __attribute__((ext_vector_type(4)));
typedef __bf16 bf16x8 __attribute__((ext_vector_type(8)));

static constexpr int HN  = 1024;     // hidden
static constexpr int VN  = 32000;    // vocab
static constexpr int BN  = 8;        // batch
static constexpr int SN  = 256;      // seq
static constexpr int H4N = 4096;     // 4*H

// ---------------------------------------------------------------------------
// xp0[t][b][r] = w_ih0[r][x[b][t]] + b_ih0[r] + b_hh0[r]
// ---------------------------------------------------------------------------
__global__ __launch_bounds__(256) void k_gather(const int* __restrict__ x,
    const float* __restrict__ w_ih0, const float* __restrict__ b_ih0,
    const float* __restrict__ b_hh0, float* __restrict__ xp) {
  int bid = blockIdx.x;
  int t = bid >> 3, b = bid & 7;
  int tok = x[b * SN + t];
  const float* col = w_ih0 + tok;           // column tok, stride VN
  float* dst = xp + (size_t)bid * H4N;
  for (int r = threadIdx.x; r < H4N; r += 256)
    dst[r] = col[(size_t)r * VN] + b_ih0[r] + b_hh0[r];
}

// ---------------------------------------------------------------------------
// device-scope grid barrier (monotonic counter; cross-XCD safe: release fence
// writes back XCD L2, acquire load invalidates; atomics are device-scope)
// ---------------------------------------------------------------------------
__device__ __forceinline__ void grid_sync(unsigned* bar, unsigned target) {
  __syncthreads();                      // drains this block's stores (vmcnt 0)
  if (threadIdx.x == 0) {
    __threadfence();                    // agent acq_rel: wbL2 so h is in LLC
    atomicAdd(bar, 1u);
    while (__hip_atomic_load(bar, __ATOMIC_ACQUIRE, __HIP_MEMORY_SCOPE_AGENT) < target)
      __builtin_amdgcn_s_sleep(1);
  }
  __syncthreads();
}

// ---------------------------------------------------------------------------
// Persistent LSTM layer. grid MUST be 256 blocks x 256 thr, 1 block/CU
// (113KB LDS enforces it). Block wg owns units [wg*4, wg*4+4).
// Per step: h [8][1024] staged to LDS; thread (ks,rg,bg) computes
// acc[4 rows][4 batches] over k in [ks*32,ks*32+32); LDS reduce over ks.
// wL/hL XOR-swizzled (bank-group varies with ks) -> 4-way max conflict.
// ---------------------------------------------------------------------------
__global__ __launch_bounds__(256, 1) void k_lstm(
    const float* __restrict__ xp,    // [S][B][4H]
    const float* __restrict__ w_hh,  // [4H][H]
    const float* __restrict__ h0,    // [B][H] (this layer)
    const float* __restrict__ c0,    // [B][H]
    float* __restrict__ hs,          // [S][B][H] out (also h exchange buffer)
    float* __restrict__ hn, float* __restrict__ cn,   // [B][H]
    unsigned* __restrict__ bar) {
  __shared__ float wL[16][1024];          // 64KB, row = g*4+u, swizzled
  __shared__ float hL[8192];              // 32KB, chunk idx (k4*8+b)^((k4>>3)&7)
  __shared__ float red[8][4][4][32];      // 16KB [rg*2+bg][ri][bi][ks]
  __shared__ float gates[16][8];
  __shared__ float cL[32];                // [u*8+b]

  const int tid = threadIdx.x;
  const int wg  = blockIdx.x;
  const int u0  = wg * 4;

  // ---- load weight slice into LDS once (iteration it = gate-row it)
  for (int it = 0; it < 16; ++it) {
    int g = it >> 2, u = it & 3;
    int k4 = tid;
    int k4s = k4 ^ ((k4 >> 3) & 7);       // swizzle within row
    f32x4 v = *(const f32x4*)&w_hh[((size_t)g * HN + u0 + u) * HN + k4 * 4];
    *(f32x4*)&wL[it][k4s * 4] = v;
  }
  if (tid < 32) cL[tid] = c0[(tid & 7) * HN + u0 + (tid >> 3)];

  const int ks = tid & 31, rg = (tid >> 5) & 3, bg = tid >> 7;
  const int ksx = ks & 7;

  for (int t = 0; t < SN; ++t) {
    // ---- stage h(t-1) -> hL (coalesced 128B global pattern, swizzled LDS)
    const float* hsrc = (t == 0) ? h0 : (hs + (size_t)(t - 1) * (BN * HN));
    #pragma unroll
    for (int it = 0; it < 8; ++it) {
      int b = tid & 7, k4 = (tid >> 3) + it * 32;
      f32x4 v = *(const f32x4*)&hsrc[b * HN + k4 * 4];
      int idx = (k4 * 8 + b) ^ ((k4 >> 3) & 7);
      *(f32x4*)&hL[idx * 4] = v;
    }
    __syncthreads();

    // ---- gate matmul partials: 512 FMA, 64 ds_read_b128 per thread
    float acc[4][4] = {};
    #pragma unroll
    for (int j = 0; j < 8; ++j) {
      int k4 = ks * 8 + j;
      int k4s = k4 ^ ksx;
      f32x4 wv[4], hv[4];
      #pragma unroll
      for (int ri = 0; ri < 4; ++ri)
        wv[ri] = *(const f32x4*)&wL[rg * 4 + ri][k4s * 4];
      #pragma unroll
      for (int bi = 0; bi < 4; ++bi) {
        int idx = ((k4 << 3) | (bg * 4 + bi)) ^ ksx;
        hv[bi] = *(const f32x4*)&hL[idx * 4];
      }
      #pragma unroll
      for (int ri = 0; ri < 4; ++ri)
        #pragma unroll
        for (int bi = 0; bi < 4; ++bi)
          acc[ri][bi] += wv[ri][0]*hv[bi][0] + wv[ri][1]*hv[bi][1]
                       + wv[ri][2]*hv[bi][2] + wv[ri][3]*hv[bi][3];
    }
    #pragma unroll
    for (int ri = 0; ri < 4; ++ri)
      #pragma unroll
      for (int bi = 0; bi < 4; ++bi)
        red[rg * 2 + bg][ri][bi][ks] = acc[ri][bi];
    __syncthreads();

    // ---- reduce over ks (128 threads: one per (gate-row, batch))
    if (tid < 128) {
      int row = tid >> 3, b = tid & 7;
      int rrg = row >> 2, ri = row & 3, bbg = b >> 2, bi = b & 3;
      const float* rp = red[rrg * 2 + bbg][ri][bi];
      float s = 0.f;
      #pragma unroll
      for (int q = 0; q < 32; ++q) s += rp[(q + tid) & 31];  // bank-rotated
      int g = row >> 2, u = row & 3;
      // careful: row = g*4+u with g=row>>2,u=row&3  (16 rows = 4g x 4u)
      s += xp[(size_t)t * (BN * H4N) + b * H4N + g * HN + u0 + u];
      gates[row][b] = s;
    }
    __syncthreads();

    // ---- nonlinearity + state update (32 threads: (u,b))
    if (tid < 32) {
      int u = tid >> 3, b = tid & 7;
      float gi = gates[0 * 4 + u][b], gf = gates[1 * 4 + u][b];
      float gg = gates[2 * 4 + u][b], go = gates[3 * 4 + u][b];
      float si = 1.f / (1.f + expf(-gi));
      float sf = 1.f / (1.f + expf(-gf));
      float so = 1.f / (1.f + expf(-go));
      float c = sf * cL[tid] + si * tanhf(gg);
      float h = so * tanhf(c);
      cL[tid] = c;
      hs[(size_t)t * (BN * HN) + b * HN + u0 + u] = h;
      if (t == SN - 1) {
        hn[b * HN + u0 + u] = h;
        cn[b * HN + u0 + u] = c;
      }
    }

    if (t != SN - 1) grid_sync(bar, 256u * (unsigned)(t + 1));
    else __syncthreads();   // hL rewrite safety not needed past end; keep sane
  }
}

// ---------------------------------------------------------------------------
// fp32 -> (bf16 hi, bf16 lo) split
// ---------------------------------------------------------------------------
__global__ __launch_bounds__(256) void k_split(const float* __restrict__ src,
    __bf16* __restrict__ hi, __bf16* __restrict__ lo) {
  int i = (blockIdx.x * 256 + threadIdx.x) * 4;
  f32x4 v = *(const f32x4*)&src[i];
  #pragma unroll
  for (int j = 0; j < 4; ++j) {
    __bf16 h = (__bf16)v[j];
    hi[i + j] = h;
    lo[i + j] = (__bf16)(v[j] - (float)h);
  }
}

// ---------------------------------------------------------------------------
// C[M=2048][N] = A[2048][1024] * Bsrc[N][1024]^T + bias1(+bias2), via
// 3-term bf16 split MFMA. 128x128 tile, BK=32, 4 waves.
// permute=1: output row m=t*8+b is written to row b*256+t (logits layout).
// ---------------------------------------------------------------------------
__global__ __launch_bounds__(256) void k_gemm(const __bf16* __restrict__ Ahi,
    const __bf16* __restrict__ Alo, const float* __restrict__ Bsrc,
    const float* __restrict__ bias1, const float* __restrict__ bias2,
    float* __restrict__ C, int Mt, int N, int permute) {
  __shared__ __bf16 sAh[128][32], sAl[128][32], sBh[128][32], sBl[128][32];
  int bid = blockIdx.x;
  int tn = bid / Mt, tm = bid % Mt;           // m-fastest: B-strip L2 reuse
  int tid = threadIdx.x, lane = tid & 63, wid = tid >> 6;
  int wr = wid >> 1, wc = wid & 1;
  f32x4 acc[4][4] = {};
  const size_t K = 1024;

  for (int kk = 0; kk < 1024; kk += 32) {
    __syncthreads();
    #pragma unroll
    for (int it = 0; it < 2; ++it) {
      int c = it * 256 + tid;                  // 512 chunks of bf16x8
      int r = c >> 2, k8 = (c & 3) * 8;
      size_t ga = (size_t)(tm * 128 + r) * K + kk + k8;
      *(bf16x8*)&sAh[r][k8] = *(const bf16x8*)&Ahi[ga];
      *(bf16x8*)&sAl[r][k8] = *(const bf16x8*)&Alo[ga];
      size_t gb = (size_t)(tn * 128 + r) * K + kk + k8;
      f32x4 x0 = *(const f32x4*)&Bsrc[gb];
      f32x4 x1 = *(const f32x4*)&Bsrc[gb + 4];
      bf16x8 bh, bl;
      #pragma unroll
      for (int j = 0; j < 4; ++j) {
        __bf16 h0 = (__bf16)x0[j]; bh[j]     = h0; bl[j]     = (__bf16)(x0[j] - (float)h0);
        __bf16 h1 = (__bf16)x1[j]; bh[4 + j] = h1; bl[4 + j] = (__bf16)(x1[j] - (float)h1);
      }
      *(bf16x8*)&sBh[r][k8] = bh;
      *(bf16x8*)&sBl[r][k8] = bl;
    }
    __syncthreads();

    int kq = (lane >> 4) * 8;
    bf16x8 ah[4], al[4], bh[4], bl[4];
    #pragma unroll
    for (int i = 0; i < 4; ++i) {
      int ra = wr * 64 + i * 16 + (lane & 15);
      ah[i] = *(const bf16x8*)&sAh[ra][kq];
      al[i] = *(const bf16x8*)&sAl[ra][kq];
      int rb = wc * 64 + i * 16 + (lane & 15);
      bh[i] = *(const bf16x8*)&sBh[rb][kq];
      bl[i] = *(const bf16x8*)&sBl[rb][kq];
    }
    #pragma unroll
    for (int i = 0; i < 4; ++i)
      #pragma unroll
      for (int j = 0; j < 4; ++j) {
        acc[i][j] = __builtin_amdgcn_mfma_f32_16x16x32_bf16(ah[i], bh[j], acc[i][j], 0, 0, 0);
        acc[i][j] = __builtin_amdgcn_mfma_f32_16x16x32_bf16(ah[i], bl[j], acc[i][j], 0, 0, 0);
        acc[i][j] = __builtin_amdgcn_mfma_f32_16x16x32_bf16(al[i], bh[j], acc[i][j], 0, 0, 0);
      }
  }

  // epilogue: C/D layout col=lane&15, row=(lane>>4)*4+reg (m89-verified)
  #pragma unroll
  for (int j = 0; j < 4; ++j) {
    int gcol = tn * 128 + wc * 64 + j * 16 + (lane & 15);
    float bv = bias1[gcol] + (bias2 ? bias2[gcol] : 0.f);
    #pragma unroll
    for (int i = 0; i < 4; ++i) {
      #pragma unroll
      for (int r = 0; r < 4; ++r) {
        int row = tm * 128 + wr * 64 + i * 16 + ((lane >> 4) << 2) + r;
        int orow = permute ? ((row & 7) * 256 + (row >> 3)) : row;
        C[(size_t)orow * N + gcol] = acc[i][j][r] + bv;
      }
    }
  }
}

// ---------------------------------------------------------------------------
extern "C" void kernel_launch(void* const* d_in, const int* in_sizes, int n_in,
                              void* d_out, int out_size, void* d_ws, size_t ws_size,
                              hipStream_t stream) {
  (void)in_sizes; (void)n_in; (void)out_size; (void)ws_size;
  const int*   x     = (const int*)  d_in[0];
  const float* h0    = (const float*)d_in[1];
  const float* c0    = (const float*)d_in[2];
  const float* w_ih0 = (const float*)d_in[3];
  const float* w_hh0 = (const float*)d_in[4];
  const float* b_ih0 = (const float*)d_in[5];
  const float* b_hh0 = (const float*)d_in[6];
  const float* w_ih1 = (const float*)d_in[7];
  const float* w_hh1 = (const float*)d_in[8];
  const float* b_ih1 = (const float*)d_in[9];
  const float* b_hh1 = (const float*)d_in[10];
  const float* fc_w  = (const float*)d_in[11];
  const float* fc_b  = (const float*)d_in[12];
  float* out = (float*)d_out;
  float* ws  = (float*)d_ws;

  // ws layout (floats)
  float* xp   = ws;                        // [S][B][4H] = 8,388,608
  float* h1s  = ws + 8388608;              // [S][B][H]  = 2,097,152
  float* h2s  = ws + 10485760;             // 2,097,152
  __bf16* Ahi = (__bf16*)(ws + 12582912);  // 2048*1024 bf16 = 1,048,576 floats
  __bf16* Alo = (__bf16*)(ws + 13631488);  // 1,048,576 floats
  unsigned* bar = (unsigned*)(ws + 14680064); // 2 counters

  const size_t LOG = (size_t)2048 * VN;    // 65,536,000
  float* hn = out + LOG;                   // [2][8][1024]
  float* cn = out + LOG + 16384;           // [2][8][1024]

  hipMemsetAsync(bar, 0, 2 * sizeof(unsigned), stream);

  k_gather<<<SN * BN, 256, 0, stream>>>(x, w_ih0, b_ih0, b_hh0, xp);

  // ---- layer 0 (persistent, 256 blocks = 256 CUs) ----
  k_lstm<<<256, 256, 0, stream>>>(xp, w_hh0, h0, c0, h1s, hn, cn, bar + 0);

  k_split<<<2048, 256, 0, stream>>>(h1s, Ahi, Alo);
  // xp1 = h1s @ w_ih1^T + (b_ih1 + b_hh1)   (M=2048, N=4096)
  k_gemm<<<16 * 32, 256, 0, stream>>>(Ahi, Alo, w_ih1, b_ih1, b_hh1, xp,
                                      16, H4N, 0);

  // ---- layer 1 ----
  k_lstm<<<256, 256, 0, stream>>>(xp, w_hh1, h0 + BN * HN, c0 + BN * HN,
                                  h2s, hn + BN * HN, cn + BN * HN, bar + 1);

  k_split<<<2048, 256, 0, stream>>>(h2s, Ahi, Alo);
  // logits = h2s @ fc_w^T + fc_b  (M=2048, N=32000), row-permuted to b*S+t
  k_gemm<<<16 * 250, 256, 0, stream>>>(Ahi, Alo, fc_w, fc_b, nullptr, out,
                                       16, VN, 1);
}

// Round 3
// 5087.724 us; speedup vs baseline: 1.8139x; 1.8139x over previous
//
#include <hip/hip_runtime.h>
#include <cmath>

typedef float  f32x4  __attribute__((ext_vector_type(4)));
typedef __bf16 bf16x8 __attribute__((ext_vector_type(8)));

static constexpr int HN  = 1024;     // hidden
static constexpr int VN  = 32000;    // vocab
static constexpr int BN  = 8;        // batch
static constexpr int SN  = 256;      // seq
static constexpr int H4N = 4096;     // 4*H

// ---------------------------------------------------------------------------
// xp0[t][b][r] = w_ih0[r][x[b][t]] + b_ih0[r] + b_hh0[r]
// ---------------------------------------------------------------------------
__global__ __launch_bounds__(256) void k_gather(const int* __restrict__ x,
    const float* __restrict__ w_ih0, const float* __restrict__ b_ih0,
    const float* __restrict__ b_hh0, float* __restrict__ xp) {
  int bid = blockIdx.x;
  int t = bid >> 3, b = bid & 7;
  int tok = x[b * SN + t];
  const float* col = w_ih0 + tok;           // column tok, stride VN
  float* dst = xp + (size_t)bid * H4N;
  for (int r = threadIdx.x; r < H4N; r += 256)
    dst[r] = col[(size_t)r * VN] + b_ih0[r] + b_hh0[r];
}

// ---------------------------------------------------------------------------
// Persistent LSTM layer. grid MUST be 256 blocks x 256 thr, 1 block/CU
// (113KB LDS enforces it). Block wg owns units [wg*4, wg*4+4).
//
// Cross-step protocol (cross-XCD safe, minimal cache damage):
//   write h : relaxed agent-scope atomic stores (write-through to MALL)
//   arrive  : same-wave s_waitcnt vmcnt(0) then RELAXED fetch_add on one of
//             8 spread counters (32 blocks each)
//   wait    : 8 lanes spin RELAXED (no inv per poll!), then ONE acquire
//             load per block per step -> single buffer_inv; then normal
//             vectorized loads see MALL data. xp refetches hit L3.
// ---------------------------------------------------------------------------
__global__ __launch_bounds__(256, 1) void k_lstm(
    const float* __restrict__ xp,    // [S][B][4H]
    const float* __restrict__ w_hh,  // [4H][H]
    const float* __restrict__ h0,    // [B][H] (this layer)
    const float* __restrict__ c0,    // [B][H]
    float* __restrict__ hs,          // [S][B][H] out (also h exchange buffer)
    float* __restrict__ hn, float* __restrict__ cn,   // [B][H]
    unsigned* __restrict__ bar) {    // 8 counters, 64B apart
  __shared__ float wL[16][1024];          // 64KB, row = g*4+u, swizzled
  __shared__ float hL[8192];              // 32KB, chunk idx (k4*8+b)^((k4>>3)&7)
  __shared__ float red[8][4][4][32];      // 16KB [rg*2+bg][ri][bi][ks]
  __shared__ float gates[16][8];
  __shared__ float cL[32];                // [u*8+b]

  const int tid = threadIdx.x;
  const int wg  = blockIdx.x;
  const int u0  = wg * 4;
  const int grp = wg & 7;

  // ---- load weight slice into LDS once
  for (int it = 0; it < 16; ++it) {
    int g = it >> 2, u = it & 3;
    int k4 = tid;
    int k4s = k4 ^ ((k4 >> 3) & 7);       // swizzle within row
    f32x4 v = *(const f32x4*)&w_hh[((size_t)g * HN + u0 + u) * HN + k4 * 4];
    *(f32x4*)&wL[it][k4s * 4] = v;
  }
  if (tid < 32) cL[tid] = c0[(tid & 7) * HN + u0 + (tid >> 3)];

  const int ks = tid & 31, rg = (tid >> 5) & 3, bg = tid >> 7;
  const int ksx = ks & 7;

  for (int t = 0; t < SN; ++t) {
    // ---- stage h(t-1) -> hL (vector loads; L2 was inv'd once last step)
    const float* hsrc = (t == 0) ? h0 : (hs + (size_t)(t - 1) * (BN * HN));
    #pragma unroll
    for (int it = 0; it < 8; ++it) {
      int b = tid & 7, k4 = (tid >> 3) + it * 32;
      f32x4 v = *(const f32x4*)&hsrc[b * HN + k4 * 4];
      int idx = (k4 * 8 + b) ^ ((k4 >> 3) & 7);
      *(f32x4*)&hL[idx * 4] = v;
    }
    __syncthreads();

    // ---- gate matmul partials: 512 FMA, 64 ds_read_b128 per thread
    float acc[4][4] = {};
    #pragma unroll
    for (int j = 0; j < 8; ++j) {
      int k4 = ks * 8 + j;
      int k4s = k4 ^ ksx;
      f32x4 wv[4], hv[4];
      #pragma unroll
      for (int ri = 0; ri < 4; ++ri)
        wv[ri] = *(const f32x4*)&wL[rg * 4 + ri][k4s * 4];
      #pragma unroll
      for (int bi = 0; bi < 4; ++bi) {
        int idx = ((k4 << 3) | (bg * 4 + bi)) ^ ksx;
        hv[bi] = *(const f32x4*)&hL[idx * 4];
      }
      #pragma unroll
      for (int ri = 0; ri < 4; ++ri)
        #pragma unroll
        for (int bi = 0; bi < 4; ++bi)
          acc[ri][bi] += wv[ri][0]*hv[bi][0] + wv[ri][1]*hv[bi][1]
                       + wv[ri][2]*hv[bi][2] + wv[ri][3]*hv[bi][3];
    }
    #pragma unroll
    for (int ri = 0; ri < 4; ++ri)
      #pragma unroll
      for (int bi = 0; bi < 4; ++bi)
        red[rg * 2 + bg][ri][bi][ks] = acc[ri][bi];
    __syncthreads();

    // ---- reduce over ks (128 threads: one per (gate-row, batch))
    if (tid < 128) {
      int row = tid >> 3, b = tid & 7;
      int rrg = row >> 2, ri = row & 3, bbg = b >> 2, bi = b & 3;
      const float* rp = red[rrg * 2 + bbg][ri][bi];
      float s = 0.f;
      #pragma unroll
      for (int q = 0; q < 32; ++q) s += rp[(q + tid) & 31];  // bank-rotated
      int g = row >> 2, u = row & 3;
      s += xp[(size_t)t * (BN * H4N) + b * H4N + g * HN + u0 + u];
      gates[row][b] = s;
    }
    __syncthreads();

    // ---- nonlinearity + state update (32 threads: (u,b), all in wave 0)
    if (tid < 32) {
      int u = tid >> 3, b = tid & 7;
      float gi = gates[0 * 4 + u][b], gf = gates[1 * 4 + u][b];
      float gg = gates[2 * 4 + u][b], go = gates[3 * 4 + u][b];
      float si = 1.f / (1.f + expf(-gi));
      float sf = 1.f / (1.f + expf(-gf));
      float so = 1.f / (1.f + expf(-go));
      float c = sf * cL[tid] + si * tanhf(gg);
      float h = so * tanhf(c);
      cL[tid] = c;
      // write-through to coherence point; no fence needed later
      __hip_atomic_store(&hs[(size_t)t * (BN * HN) + b * HN + u0 + u], h,
                         __ATOMIC_RELAXED, __HIP_MEMORY_SCOPE_AGENT);
      if (t == SN - 1) {
        hn[b * HN + u0 + u] = h;   // normal: kernel-end flush covers these
        cn[b * HN + u0 + u] = c;
      }
    }

    if (t != SN - 1) {
      // ---- arrive (tid0 is in wave 0, same wave as the h-stores above:
      //      vmcnt(0) orders the sc1 stores at the coherence point)
      if (tid == 0) {
        asm volatile("s_waitcnt vmcnt(0)" ::: "memory");
        __hip_atomic_fetch_add(&bar[grp * 16], 1u,
                               __ATOMIC_RELAXED, __HIP_MEMORY_SCOPE_AGENT);
      }
      // ---- wait: relaxed spin on all 8 counters (one lane each)
      if (tid < 8) {
        unsigned tgt = 32u * (unsigned)(t + 1);
        while (__hip_atomic_load(&bar[tid * 16], __ATOMIC_RELAXED,
                                 __HIP_MEMORY_SCOPE_AGENT) < tgt)
          __builtin_amdgcn_s_sleep(1);
      }
      __syncthreads();
      // ---- single acquire per block per step: one buffer_inv, so the
      //      normal vector loads below see the MALL data
      if (tid == 0)
        (void)__hip_atomic_load(&bar[grp * 16], __ATOMIC_ACQUIRE,
                                __HIP_MEMORY_SCOPE_AGENT);
      __syncthreads();
    } else {
      __syncthreads();
    }
  }
}

// ---------------------------------------------------------------------------
// fp32 -> (bf16 hi, bf16 lo) split
// ---------------------------------------------------------------------------
__global__ __launch_bounds__(256) void k_split(const float* __restrict__ src,
    __bf16* __restrict__ hi, __bf16* __restrict__ lo) {
  int i = (blockIdx.x * 256 + threadIdx.x) * 4;
  f32x4 v = *(const f32x4*)&src[i];
  #pragma unroll
  for (int j = 0; j < 4; ++j) {
    __bf16 h = (__bf16)v[j];
    hi[i + j] = h;
    lo[i + j] = (__bf16)(v[j] - (float)h);
  }
}

// ---------------------------------------------------------------------------
// C[M=2048][N] = A[2048][1024] * Bsrc[N][1024]^T + bias1(+bias2), via
// 3-term bf16 split MFMA. 128x128 tile, BK=32, 4 waves.
// permute=1: output row m=t*8+b is written to row b*256+t (logits layout).
// ---------------------------------------------------------------------------
__global__ __launch_bounds__(256) void k_gemm(const __bf16* __restrict__ Ahi,
    const __bf16* __restrict__ Alo, const float* __restrict__ Bsrc,
    const float* __restrict__ bias1, const float* __restrict__ bias2,
    float* __restrict__ C, int Mt, int N, int permute) {
  __shared__ __bf16 sAh[128][32], sAl[128][32], sBh[128][32], sBl[128][32];
  int bid = blockIdx.x;
  int tn = bid / Mt, tm = bid % Mt;           // m-fastest: B-strip L2 reuse
  int tid = threadIdx.x, lane = tid & 63, wid = tid >> 6;
  int wr = wid >> 1, wc = wid & 1;
  f32x4 acc[4][4] = {};
  const size_t K = 1024;

  for (int kk = 0; kk < 1024; kk += 32) {
    __syncthreads();
    #pragma unroll
    for (int it = 0; it < 2; ++it) {
      int c = it * 256 + tid;                  // 512 chunks of bf16x8
      int r = c >> 2, k8 = (c & 3) * 8;
      size_t ga = (size_t)(tm * 128 + r) * K + kk + k8;
      *(bf16x8*)&sAh[r][k8] = *(const bf16x8*)&Ahi[ga];
      *(bf16x8*)&sAl[r][k8] = *(const bf16x8*)&Alo[ga];
      size_t gb = (size_t)(tn * 128 + r) * K + kk + k8;
      f32x4 x0 = *(const f32x4*)&Bsrc[gb];
      f32x4 x1 = *(const f32x4*)&Bsrc[gb + 4];
      bf16x8 bh, bl;
      #pragma unroll
      for (int j = 0; j < 4; ++j) {
        __bf16 h0 = (__bf16)x0[j]; bh[j]     = h0; bl[j]     = (__bf16)(x0[j] - (float)h0);
        __bf16 h1 = (__bf16)x1[j]; bh[4 + j] = h1; bl[4 + j] = (__bf16)(x1[j] - (float)h1);
      }
      *(bf16x8*)&sBh[r][k8] = bh;
      *(bf16x8*)&sBl[r][k8] = bl;
    }
    __syncthreads();

    int kq = (lane >> 4) * 8;
    bf16x8 ah[4], al[4], bh[4], bl[4];
    #pragma unroll
    for (int i = 0; i < 4; ++i) {
      int ra = wr * 64 + i * 16 + (lane & 15);
      ah[i] = *(const bf16x8*)&sAh[ra][kq];
      al[i] = *(const bf16x8*)&sAl[ra][kq];
      int rb = wc * 64 + i * 16 + (lane & 15);
      bh[i] = *(const bf16x8*)&sBh[rb][kq];
      bl[i] = *(const bf16x8*)&sBl[rb][kq];
    }
    #pragma unroll
    for (int i = 0; i < 4; ++i)
      #pragma unroll
      for (int j = 0; j < 4; ++j) {
        acc[i][j] = __builtin_amdgcn_mfma_f32_16x16x32_bf16(ah[i], bh[j], acc[i][j], 0, 0, 0);
        acc[i][j] = __builtin_amdgcn_mfma_f32_16x16x32_bf16(ah[i], bl[j], acc[i][j], 0, 0, 0);
        acc[i][j] = __builtin_amdgcn_mfma_f32_16x16x32_bf16(al[i], bh[j], acc[i][j], 0, 0, 0);
      }
  }

  // epilogue: C/D layout col=lane&15, row=(lane>>4)*4+reg (m89-verified)
  #pragma unroll
  for (int j = 0; j < 4; ++j) {
    int gcol = tn * 128 + wc * 64 + j * 16 + (lane & 15);
    float bv = bias1[gcol] + (bias2 ? bias2[gcol] : 0.f);
    #pragma unroll
    for (int i = 0; i < 4; ++i) {
      #pragma unroll
      for (int r = 0; r < 4; ++r) {
        int row = tm * 128 + wr * 64 + i * 16 + ((lane >> 4) << 2) + r;
        int orow = permute ? ((row & 7) * 256 + (row >> 3)) : row;
        C[(size_t)orow * N + gcol] = acc[i][j][r] + bv;
      }
    }
  }
}

// ---------------------------------------------------------------------------
extern "C" void kernel_launch(void* const* d_in, const int* in_sizes, int n_in,
                              void* d_out, int out_size, void* d_ws, size_t ws_size,
                              hipStream_t stream) {
  (void)in_sizes; (void)n_in; (void)out_size; (void)ws_size;
  const int*   x     = (const int*)  d_in[0];
  const float* h0    = (const float*)d_in[1];
  const float* c0    = (const float*)d_in[2];
  const float* w_ih0 = (const float*)d_in[3];
  const float* w_hh0 = (const float*)d_in[4];
  const float* b_ih0 = (const float*)d_in[5];
  const float* b_hh0 = (const float*)d_in[6];
  const float* w_ih1 = (const float*)d_in[7];
  const float* w_hh1 = (const float*)d_in[8];
  const float* b_ih1 = (const float*)d_in[9];
  const float* b_hh1 = (const float*)d_in[10];
  const float* fc_w  = (const float*)d_in[11];
  const float* fc_b  = (const float*)d_in[12];
  float* out = (float*)d_out;
  float* ws  = (float*)d_ws;

  // ws layout (floats)
  float* xp   = ws;                        // [S][B][4H] = 8,388,608
  float* h1s  = ws + 8388608;              // [S][B][H]  = 2,097,152
  float* h2s  = ws + 10485760;             // 2,097,152
  __bf16* Ahi = (__bf16*)(ws + 12582912);  // 2048*1024 bf16 = 1,048,576 floats
  __bf16* Alo = (__bf16*)(ws + 13631488);  // 1,048,576 floats
  unsigned* bar = (unsigned*)(ws + 14680064); // 256 uints: 2 layers x 8 x 16

  const size_t LOG = (size_t)2048 * VN;    // 65,536,000
  float* hn = out + LOG;                   // [2][8][1024]
  float* cn = out + LOG + 16384;           // [2][8][1024]

  hipMemsetAsync(bar, 0, 256 * sizeof(unsigned), stream);

  k_gather<<<SN * BN, 256, 0, stream>>>(x, w_ih0, b_ih0, b_hh0, xp);

  // ---- layer 0 (persistent, 256 blocks = 256 CUs) ----
  k_lstm<<<256, 256, 0, stream>>>(xp, w_hh0, h0, c0, h1s, hn, cn, bar);

  k_split<<<2048, 256, 0, stream>>>(h1s, Ahi, Alo);
  // xp1 = h1s @ w_ih1^T + (b_ih1 + b_hh1)   (M=2048, N=4096)
  k_gemm<<<16 * 32, 256, 0, stream>>>(Ahi, Alo, w_ih1, b_ih1, b_hh1, xp,
                                      16, H4N, 0);

  // ---- layer 1 ----
  k_lstm<<<256, 256, 0, stream>>>(xp, w_hh1, h0 + BN * HN, c0 + BN * HN,
                                  h2s, hn + BN * HN, cn + BN * HN, bar + 128);

  k_split<<<2048, 256, 0, stream>>>(h2s, Ahi, Alo);
  // logits = h2s @ fc_w^T + fc_b  (M=2048, N=32000), row-permuted to b*S+t
  k_gemm<<<16 * 250, 256, 0, stream>>>(Ahi, Alo, fc_w, fc_b, nullptr, out,
                                       16, VN, 1);
}

// Round 5
// 4245.650 us; speedup vs baseline: 2.1737x; 1.1983x over previous
//
#include <hip/hip_runtime.h>
#include <cmath>

typedef float  f32x4  __attribute__((ext_vector_type(4)));
typedef float  f32x2  __attribute__((ext_vector_type(2)));
typedef __bf16 bf16x8 __attribute__((ext_vector_type(8)));

static constexpr int HN  = 1024;     // hidden
static constexpr int VN  = 32000;    // vocab
static constexpr int BN  = 8;        // batch
static constexpr int SN  = 256;      // seq
static constexpr int H4N = 4096;     // 4*H

// ---------------------------------------------------------------------------
// xp0[t][b][r] = w_ih0[r][x[b][t]] + b_ih0[r] + b_hh0[r]
// ---------------------------------------------------------------------------
__global__ __launch_bounds__(256) void k_gather(const int* __restrict__ x,
    const float* __restrict__ w_ih0, const float* __restrict__ b_ih0,
    const float* __restrict__ b_hh0, float* __restrict__ xp) {
  int bid = blockIdx.x;
  int t = bid >> 3, b = bid & 7;
  int tok = x[b * SN + t];
  const float* col = w_ih0 + tok;           // column tok, stride VN
  float* dst = xp + (size_t)bid * H4N;
  for (int r = threadIdx.x; r < H4N; r += 256)
    dst[r] = col[(size_t)r * VN] + b_ih0[r] + b_hh0[r];
}

// ---------------------------------------------------------------------------
// Persistent LSTM layer. grid MUST be 256 blocks x 256 thr, 1 block/CU
// (113KB LDS enforces it). Block wg owns units [wg*4, wg*4+4).
//
// Cross-step protocol (cross-XCD safe, ZERO cache invalidation):
//   write h : relaxed agent-scope atomic stores (sc1 write-through -> MALL)
//   arrive  : same-wave s_waitcnt vmcnt(0), then RELAXED fetch_add on one of
//             64 counters (4 blocks each, 128B apart) -> fan-in 4 not 256
//   wait    : 64 lanes of wave 0 spin RELAXED, one counter per lane (no inv)
//   read h  : relaxed agent-scope atomic u64 loads (sc1: read MALL directly;
//             stale local L1/L2 can't serve them), so xp/w_hh stay warm in
//             L2 across all 256 steps and no acquire/invalidate is needed.
// ---------------------------------------------------------------------------
__global__ __launch_bounds__(256, 1) void k_lstm(
    const float* __restrict__ xp,    // [S][B][4H]
    const float* __restrict__ w_hh,  // [4H][H]
    const float* __restrict__ h0,    // [B][H] (this layer)
    const float* __restrict__ c0,    // [B][H]
    float* __restrict__ hs,          // [S][B][H] out (also h exchange buffer)
    float* __restrict__ hn, float* __restrict__ cn,   // [B][H]
    unsigned* __restrict__ bar) {    // 64 counters, stride 32 uints (128B)
  __shared__ float wL[16][1024];          // 64KB, row = g*4+u, swizzled
  __shared__ float hL[8192];              // 32KB, chunk idx (k4*8+b)^((k4>>3)&7)
  __shared__ float red[8][4][4][32];      // 16KB [rg*2+bg][ri][bi][ks]
  __shared__ float gates[16][8];
  __shared__ float cL[32];                // [u*8+b]

  const int tid = threadIdx.x;
  const int wg  = blockIdx.x;
  const int u0  = wg * 4;

  // ---- load weight slice into LDS once
  for (int it = 0; it < 16; ++it) {
    int g = it >> 2, u = it & 3;
    int k4 = tid;
    int k4s = k4 ^ ((k4 >> 3) & 7);       // swizzle within row
    f32x4 v = *(const f32x4*)&w_hh[((size_t)g * HN + u0 + u) * HN + k4 * 4];
    *(f32x4*)&wL[it][k4s * 4] = v;
  }
  if (tid < 32) cL[tid] = c0[(tid & 7) * HN + u0 + (tid >> 3)];

  const int ks = tid & 31, rg = (tid >> 5) & 3, bg = tid >> 7;
  const int ksx = ks & 7;
  const int hb = tid & 7;                  // batch row this thread stages
  const int hk = tid >> 3;                 // u64 lane within row, 0..31

  for (int t = 0; t < SN; ++t) {
    // ---- stage h(t-1) -> hL via agent-scope (sc1/MALL) u64 loads
    const float* hsrc = (t == 0) ? h0 : (hs + (size_t)(t - 1) * (BN * HN));
    const unsigned long long* hsrc8 =
        (const unsigned long long*)hsrc + (size_t)hb * 512 + hk;
    unsigned long long rv[16];
    #pragma unroll
    for (int j = 0; j < 16; ++j)
      rv[j] = __hip_atomic_load((unsigned long long*)(hsrc8 + j * 32),
                                __ATOMIC_RELAXED, __HIP_MEMORY_SCOPE_AGENT);
    #pragma unroll
    for (int j = 0; j < 16; ++j) {
      int k64 = hk + j * 32;               // u64 index within the row
      int k4 = k64 >> 1, half = k64 & 1;
      int idx = ((k4 << 3) | hb) ^ ((k4 >> 3) & 7);
      *(f32x2*)&hL[idx * 4 + half * 2] = __builtin_bit_cast(f32x2, rv[j]);
    }
    __syncthreads();

    // ---- gate matmul partials: 512 FMA, 64 ds_read_b128 per thread
    float acc[4][4] = {};
    #pragma unroll
    for (int j = 0; j < 8; ++j) {
      int k4 = ks * 8 + j;
      int k4s = k4 ^ ksx;
      f32x4 wv[4], hv[4];
      #pragma unroll
      for (int ri = 0; ri < 4; ++ri)
        wv[ri] = *(const f32x4*)&wL[rg * 4 + ri][k4s * 4];
      #pragma unroll
      for (int bi = 0; bi < 4; ++bi) {
        int idx = ((k4 << 3) | (bg * 4 + bi)) ^ ksx;
        hv[bi] = *(const f32x4*)&hL[idx * 4];
      }
      #pragma unroll
      for (int ri = 0; ri < 4; ++ri)
        #pragma unroll
        for (int bi = 0; bi < 4; ++bi)
          acc[ri][bi] += wv[ri][0]*hv[bi][0] + wv[ri][1]*hv[bi][1]
                       + wv[ri][2]*hv[bi][2] + wv[ri][3]*hv[bi][3];
    }
    #pragma unroll
    for (int ri = 0; ri < 4; ++ri)
      #pragma unroll
      for (int bi = 0; bi < 4; ++bi)
        red[rg * 2 + bg][ri][bi][ks] = acc[ri][bi];
    __syncthreads();

    // ---- reduce over ks (128 threads: one per (gate-row, batch))
    if (tid < 128) {
      int row = tid >> 3, b = tid & 7;
      int rrg = row >> 2, ri = row & 3, bbg = b >> 2, bi = b & 3;
      const float* rp = red[rrg * 2 + bbg][ri][bi];
      float s = 0.f;
      #pragma unroll
      for (int q = 0; q < 32; ++q) s += rp[(q + tid) & 31];  // bank-rotated
      int g = row >> 2, u = row & 3;
      s += xp[(size_t)t * (BN * H4N) + b * H4N + g * HN + u0 + u];
      gates[row][b] = s;
    }
    __syncthreads();

    // ---- nonlinearity + state update (32 threads: (u,b), all in wave 0)
    if (tid < 32) {
      int u = tid >> 3, b = tid & 7;
      float gi = gates[0 * 4 + u][b], gf = gates[1 * 4 + u][b];
      float gg = gates[2 * 4 + u][b], go = gates[3 * 4 + u][b];
      float si = 1.f / (1.f + expf(-gi));
      float sf = 1.f / (1.f + expf(-gf));
      float so = 1.f / (1.f + expf(-go));
      float c = sf * cL[tid] + si * tanhf(gg);
      float h = so * tanhf(c);
      cL[tid] = c;
      // write-through to coherence point (sc1)
      __hip_atomic_store(&hs[(size_t)t * (BN * HN) + b * HN + u0 + u], h,
                         __ATOMIC_RELAXED, __HIP_MEMORY_SCOPE_AGENT);
      if (t == SN - 1) {
        hn[b * HN + u0 + u] = h;
        cn[b * HN + u0 + u] = c;
      }
    }

    if (t != SN - 1) {
      // ---- arrive: tid0 shares wave 0 with the 32 h-store lanes, so
      //      vmcnt(0) orders those sc1 stores at the MALL before the add
      if (tid == 0) {
        asm volatile("s_waitcnt vmcnt(0)" ::: "memory");
        __hip_atomic_fetch_add(&bar[(wg >> 2) * 32], 1u,
                               __ATOMIC_RELAXED, __HIP_MEMORY_SCOPE_AGENT);
      }
      // ---- wait: 64 lanes, one counter each, relaxed spin (no inv)
      if (tid < 64) {
        unsigned tgt = 4u * (unsigned)(t + 1);
        while (__hip_atomic_load(&bar[tid * 32], __ATOMIC_RELAXED,
                                 __HIP_MEMORY_SCOPE_AGENT) < tgt)
          __builtin_amdgcn_s_sleep(1);
      }
      __syncthreads();
    } else {
      __syncthreads();
    }
  }
}

// ---------------------------------------------------------------------------
// fp32 -> (bf16 hi, bf16 lo) split
// ---------------------------------------------------------------------------
__global__ __launch_bounds__(256) void k_split(const float* __restrict__ src,
    __bf16* __restrict__ hi, __bf16* __restrict__ lo) {
  int i = (blockIdx.x * 256 + threadIdx.x) * 4;
  f32x4 v = *(const f32x4*)&src[i];
  #pragma unroll
  for (int j = 0; j < 4; ++j) {
    __bf16 h = (__bf16)v[j];
    hi[i + j] = h;
    lo[i + j] = (__bf16)(v[j] - (float)h);
  }
}

// ---------------------------------------------------------------------------
// C[M=2048][N] = A[2048][1024] * Bsrc[N][1024]^T + bias1(+bias2), via
// 3-term bf16 split MFMA. 128x128 tile, BK=32, 4 waves.
// permute=1: output row m=t*8+b is written to row b*256+t (logits layout).
// ---------------------------------------------------------------------------
__global__ __launch_bounds__(256) void k_gemm(const __bf16* __restrict__ Ahi,
    const __bf16* __restrict__ Alo, const float* __restrict__ Bsrc,
    const float* __restrict__ bias1, const float* __restrict__ bias2,
    float* __restrict__ C, int Mt, int N, int permute) {
  __shared__ __bf16 sAh[128][32], sAl[128][32], sBh[128][32], sBl[128][32];
  int bid = blockIdx.x;
  int tn = bid / Mt, tm = bid % Mt;           // m-fastest: B-strip L2 reuse
  int tid = threadIdx.x, lane = tid & 63, wid = tid >> 6;
  int wr = wid >> 1, wc = wid & 1;
  f32x4 acc[4][4] = {};
  const size_t K = 1024;

  for (int kk = 0; kk < 1024; kk += 32) {
    __syncthreads();
    #pragma unroll
    for (int it = 0; it < 2; ++it) {
      int c = it * 256 + tid;                  // 512 chunks of bf16x8
      int r = c >> 2, k8 = (c & 3) * 8;
      size_t ga = (size_t)(tm * 128 + r) * K + kk + k8;
      *(bf16x8*)&sAh[r][k8] = *(const bf16x8*)&Ahi[ga];
      *(bf16x8*)&sAl[r][k8] = *(const bf16x8*)&Alo[ga];
      size_t gb = (size_t)(tn * 128 + r) * K + kk + k8;
      f32x4 x0 = *(const f32x4*)&Bsrc[gb];
      f32x4 x1 = *(const f32x4*)&Bsrc[gb + 4];
      bf16x8 bh, bl;
      #pragma unroll
      for (int j = 0; j < 4; ++j) {
        __bf16 h0 = (__bf16)x0[j]; bh[j]     = h0; bl[j]     = (__bf16)(x0[j] - (float)h0);
        __bf16 h1 = (__bf16)x1[j]; bh[4 + j] = h1; bl[4 + j] = (__bf16)(x1[j] - (float)h1);
      }
      *(bf16x8*)&sBh[r][k8] = bh;
      *(bf16x8*)&sBl[r][k8] = bl;
    }
    __syncthreads();

    int kq = (lane >> 4) * 8;
    bf16x8 ah[4], al[4], bh[4], bl[4];
    #pragma unroll
    for (int i = 0; i < 4; ++i) {
      int ra = wr * 64 + i * 16 + (lane & 15);
      ah[i] = *(const bf16x8*)&sAh[ra][kq];
      al[i] = *(const bf16x8*)&sAl[ra][kq];
      int rb = wc * 64 + i * 16 + (lane & 15);
      bh[i] = *(const bf16x8*)&sBh[rb][kq];
      bl[i] = *(const bf16x8*)&sBl[rb][kq];
    }
    #pragma unroll
    for (int i = 0; i < 4; ++i)
      #pragma unroll
      for (int j = 0; j < 4; ++j) {
        acc[i][j] = __builtin_amdgcn_mfma_f32_16x16x32_bf16(ah[i], bh[j], acc[i][j], 0, 0, 0);
        acc[i][j] = __builtin_amdgcn_mfma_f32_16x16x32_bf16(ah[i], bl[j], acc[i][j], 0, 0, 0);
        acc[i][j] = __builtin_amdgcn_mfma_f32_16x16x32_bf16(al[i], bh[j], acc[i][j], 0, 0, 0);
      }
  }

  // epilogue: C/D layout col=lane&15, row=(lane>>4)*4+reg (m89-verified)
  #pragma unroll
  for (int j = 0; j < 4; ++j) {
    int gcol = tn * 128 + wc * 64 + j * 16 + (lane & 15);
    float bv = bias1[gcol] + (bias2 ? bias2[gcol] : 0.f);
    #pragma unroll
    for (int i = 0; i < 4; ++i) {
      #pragma unroll
      for (int r = 0; r < 4; ++r) {
        int row = tm * 128 + wr * 64 + i * 16 + ((lane >> 4) << 2) + r;
        int orow = permute ? ((row & 7) * 256 + (row >> 3)) : row;
        C[(size_t)orow * N + gcol] = acc[i][j][r] + bv;
      }
    }
  }
}

// ---------------------------------------------------------------------------
extern "C" void kernel_launch(void* const* d_in, const int* in_sizes, int n_in,
                              void* d_out, int out_size, void* d_ws, size_t ws_size,
                              hipStream_t stream) {
  (void)in_sizes; (void)n_in; (void)out_size; (void)ws_size;
  const int*   x     = (const int*)  d_in[0];
  const float* h0    = (const float*)d_in[1];
  const float* c0    = (const float*)d_in[2];
  const float* w_ih0 = (const float*)d_in[3];
  const float* w_hh0 = (const float*)d_in[4];
  const float* b_ih0 = (const float*)d_in[5];
  const float* b_hh0 = (const float*)d_in[6];
  const float* w_ih1 = (const float*)d_in[7];
  const float* w_hh1 = (const float*)d_in[8];
  const float* b_ih1 = (const float*)d_in[9];
  const float* b_hh1 = (const float*)d_in[10];
  const float* fc_w  = (const float*)d_in[11];
  const float* fc_b  = (const float*)d_in[12];
  float* out = (float*)d_out;
  float* ws  = (float*)d_ws;

  // ws layout (floats)
  float* xp   = ws;                        // [S][B][4H] = 8,388,608
  float* h1s  = ws + 8388608;              // [S][B][H]  = 2,097,152
  float* h2s  = ws + 10485760;             // 2,097,152
  __bf16* Ahi = (__bf16*)(ws + 12582912);  // 2048*1024 bf16 = 1,048,576 floats
  __bf16* Alo = (__bf16*)(ws + 13631488);  // 1,048,576 floats
  unsigned* bar = (unsigned*)(ws + 14680064); // 4096 uints: 2 layers x 64 x 32

  const size_t LOG = (size_t)2048 * VN;    // 65,536,000
  float* hn = out + LOG;                   // [2][8][1024]
  float* cn = out + LOG + 16384;           // [2][8][1024]

  hipMemsetAsync(bar, 0, 4096 * sizeof(unsigned), stream);

  k_gather<<<SN * BN, 256, 0, stream>>>(x, w_ih0, b_ih0, b_hh0, xp);

  // ---- layer 0 (persistent, 256 blocks = 256 CUs) ----
  k_lstm<<<256, 256, 0, stream>>>(xp, w_hh0, h0, c0, h1s, hn, cn, bar);

  k_split<<<2048, 256, 0, stream>>>(h1s, Ahi, Alo);
  // xp1 = h1s @ w_ih1^T + (b_ih1 + b_hh1)   (M=2048, N=4096)
  k_gemm<<<16 * 32, 256, 0, stream>>>(Ahi, Alo, w_ih1, b_ih1, b_hh1, xp,
                                      16, H4N, 0);

  // ---- layer 1 ----
  k_lstm<<<256, 256, 0, stream>>>(xp, w_hh1, h0 + BN * HN, c0 + BN * HN,
                                  h2s, hn + BN * HN, cn + BN * HN, bar + 2048);

  k_split<<<2048, 256, 0, stream>>>(h2s, Ahi, Alo);
  // logits = h2s @ fc_w^T + fc_b  (M=2048, N=32000), row-permuted to b*S+t
  k_gemm<<<16 * 250, 256, 0, stream>>>(Ahi, Alo, fc_w, fc_b, nullptr, out,
                                       16, VN, 1);
}